// Round 9
// baseline (257.774 us; speedup 1.0000x reference)
//
#include <hip/hip_runtime.h>
#include <math.h>

constexpr int DIM = 64;
constexpr int S = 8;
constexpr int WPB = 16;                // 1024-thread blocks (R7 geometry win)
constexpr int BLOCK = WPB * 64;
constexpr int GRID = 512;              // 2 blocks/CU x 256 CU; grid-stride over batch
constexpr int BSTR = 36;               // W^T row stride in dwords: 144B/lane -> 16B-aligned b128;
                                       // 8-lane groups span all 32 banks -> conflict-free

typedef _Float16 h2_t __attribute__((ext_vector_type(2)));

// DPP quad-perm lane exchange (VALU pipe, not DS) — correctness verified R3-R7
template <int CTRL>
__device__ __forceinline__ float dppx(float x) {
    return __builtin_bit_cast(float,
        __builtin_amdgcn_mov_dpp(__builtin_bit_cast(int, x), CTRL, 0xf, 0xf, true));
}
#define XOR1 0xB1   // quad_perm(1,0,3,2)
#define XOR2 0x4E   // quad_perm(2,3,0,1)

__device__ __forceinline__ unsigned pk_f16(float a, float b) {
    return __builtin_bit_cast(unsigned, __builtin_amdgcn_cvt_pkrtz(a, b));
}
__device__ __forceinline__ float fdot2(unsigned a, unsigned b, float c) {
    return __builtin_amdgcn_fdot2(__builtin_bit_cast(h2_t, a), __builtin_bit_cast(h2_t, b), c, false);
}

// 8-way softmax pieces over lanes' (lane&7) scores: returns per-lane numerator e,
// writes uniform 1/sum to *inv. Weights distributed via per-wave LDS strip.
__device__ __forceinline__ float octet_e(float sc, float* inv) {
    float m = sc;
    m = fmaxf(m, dppx<XOR1>(m));
    m = fmaxf(m, dppx<XOR2>(m));
    m = fmaxf(m, __shfl_xor(m, 4));
    float e = __expf(sc - m);
    float s = e;
    s += dppx<XOR1>(s);
    s += dppx<XOR2>(s);
    s += __shfl_xor(s, 4);
    *inv = 1.0f / s;
    return e;
}

__global__ __launch_bounds__(BLOCK)
void sestkgcn_kernel(
    const int*   __restrict__ u_idx,
    const int*   __restrict__ v_idx,
    const float* __restrict__ usr_feat,
    const float* __restrict__ item_feat,
    const float* __restrict__ rel_feat,
    const int*   __restrict__ neigh_uu,
    const float* __restrict__ neigh_uu_st,
    const int*   __restrict__ neigh_ui,
    const float* __restrict__ neigh_ui_rat,
    const float* __restrict__ neigh_ui_vot,
    const float* __restrict__ neigh_ui_tim,
    const int*   __restrict__ neigh_iu,
    const float* __restrict__ neigh_iu_rat,
    const float* __restrict__ neigh_iu_vot,
    const float* __restrict__ neigh_iu_tim,
    const int*   __restrict__ neigh_ii,
    const int*   __restrict__ neigh_ir,
    const float* __restrict__ Wu,
    const float* __restrict__ bu,
    const float* __restrict__ Wv,
    const float* __restrict__ bv,
    float*       __restrict__ out,
    int n)
{
    // f16-packed W^T: sWuP[j*BSTR + m] = {f16 Wu[2m][j], f16 Wu[2m+1][j]}, m=0..31
    __shared__ unsigned sWuP[DIM * BSTR];
    __shared__ unsigned sWvP[DIM * BSTR];
    __shared__ float sbu[DIM];
    __shared__ float sbv[DIM];
    __shared__ unsigned xsh[WPB * 32];   // per-wave f16-packed x (32 dwords)
    __shared__ float es[WPB * 8];        // per-wave softmax-numerator strip

    const int tid = threadIdx.x;
    for (int i = tid; i < DIM * 32; i += BLOCK) {
        const int j_ = i & 63, m_ = i >> 6;          // dims 2m, 2m+1
        sWuP[j_ * BSTR + m_] = pk_f16(Wu[(2 * m_) * DIM + j_], Wu[(2 * m_ + 1) * DIM + j_]);
        sWvP[j_ * BSTR + m_] = pk_f16(Wv[(2 * m_) * DIM + j_], Wv[(2 * m_ + 1) * DIM + j_]);
    }
    if (tid < DIM) { sbu[tid] = bu[tid]; sbv[tid] = bv[tid]; }
    __syncthreads();

    const int wave = tid >> 6;
    const int lane = tid & 63;
    const int ls   = lane & 7;

    const uint4* wuQ = (const uint4*)&sWuP[lane * BSTR];
    const uint4* wvQ = (const uint4*)&sWvP[lane * BSTR];
    unsigned*    xh  = &xsh[wave * 32];
    const uint4* xhQ = (const uint4*)xh;
    float*       ew  = &es[wave * 8];
    const float4* ewQ = (const float4*)ew;
    const float bu_l = sbu[lane];
    const float bv_l = sbv[lane];

    const int stride = GRID * WPB;
    int b = blockIdx.x * WPB + wave;
    if (b >= n) return;

    int u = u_idx[b];
    int v = v_idx[b];

    while (b < n) {
        const int b2 = b + stride;
        const int bc = (b2 < n) ? b2 : b;
        const int u_nxt = u_idx[bc];
        const int v_nxt = v_idx[bc];

        const unsigned u8 = (unsigned)u << 3, v8 = (unsigned)v << 3;

        const float u_d = usr_feat[((unsigned)u << 6) | (unsigned)lane];
        const float v_d = item_feat[((unsigned)v << 6) | (unsigned)lane];

        const float sc_uu = neigh_uu_st[u8 + ls];
        const float sc_ui = neigh_ui_rat[u8 + ls] * neigh_ui_vot[u8 + ls] * neigh_ui_tim[u8 + ls];
        const float sc_iu = neigh_iu_rat[v8 + ls] * neigh_iu_vot[v8 + ls] * neigh_iu_tim[v8 + ls];

        // ---------------- user side ----------------
        float agg_uu = 0.f;
        {
            float inv;
            const float e = octet_e(sc_uu, &inv);
            __threadfence_block();
            if (lane < 8) ew[lane] = e;
            __threadfence_block();
            const float4 eA = ewQ[0], eB = ewQ[1];
            const int4 i0 = ((const int4*)(neigh_uu + u8))[0];
            const int4 i1 = ((const int4*)(neigh_uu + u8))[1];
            const int ni[S] = {i0.x, i0.y, i0.z, i0.w, i1.x, i1.y, i1.z, i1.w};
            const float wv[S] = {eA.x, eA.y, eA.z, eA.w, eB.x, eB.y, eB.z, eB.w};
            float acc = 0.f;
            #pragma unroll
            for (int s = 0; s < S; s++)
                acc = fmaf(wv[s], usr_feat[((unsigned)ni[s] << 6) | (unsigned)lane], acc);
            agg_uu = acc * inv;
        }

        float agg_ui = 0.f;
        {
            float inv;
            const float e = octet_e(sc_ui, &inv);
            __threadfence_block();
            if (lane < 8) ew[lane] = e;
            __threadfence_block();
            const float4 eA = ewQ[0], eB = ewQ[1];
            const int4 i0 = ((const int4*)(neigh_ui + u8))[0];
            const int4 i1 = ((const int4*)(neigh_ui + u8))[1];
            const int ni[S] = {i0.x, i0.y, i0.z, i0.w, i1.x, i1.y, i1.z, i1.w};
            const float wv[S] = {eA.x, eA.y, eA.z, eA.w, eB.x, eB.y, eB.z, eB.w};
            float acc = 0.f;
            #pragma unroll
            for (int s = 0; s < S; s++)
                acc = fmaf(wv[s], item_feat[((unsigned)ni[s] << 6) | (unsigned)lane], acc);
            agg_ui = acc * inv;
        }

        // user_h = relu(x @ Wu + bu): f16-packed x (pairs 2m,2m+1) + f16-packed W + v_dot2
        float hu;
        {
            const float xf = u_d + agg_uu + agg_ui;
            const float xn = dppx<XOR1>(xf);          // neighbor's x
            __threadfence_block();
            if (!(lane & 1)) xh[lane >> 1] = pk_f16(xf, xn);
            __threadfence_block();
            float a0 = 0.f, a1 = 0.f, a2 = 0.f, a3 = 0.f;
            #pragma unroll
            for (int k = 0; k < 8; k++) {
                const uint4 wq = wuQ[k];
                const uint4 xq = xhQ[k];
                a0 = fdot2(wq.x, xq.x, a0);
                a1 = fdot2(wq.y, xq.y, a1);
                a2 = fdot2(wq.z, xq.z, a2);
                a3 = fdot2(wq.w, xq.w, a3);
            }
            hu = fmaxf((a0 + a1) + (a2 + a3) + bu_l, 0.f);
        }

        // ---------------- item side ----------------
        float agg_iu = 0.f;
        {
            float inv;
            const float e = octet_e(sc_iu, &inv);
            __threadfence_block();
            if (lane < 8) ew[lane] = e;
            __threadfence_block();
            const float4 eA = ewQ[0], eB = ewQ[1];
            const int4 i0 = ((const int4*)(neigh_iu + v8))[0];
            const int4 i1 = ((const int4*)(neigh_iu + v8))[1];
            const int ni[S] = {i0.x, i0.y, i0.z, i0.w, i1.x, i1.y, i1.z, i1.w};
            const float wv[S] = {eA.x, eA.y, eA.z, eA.w, eB.x, eB.y, eB.z, eB.w};
            float acc = 0.f;
            #pragma unroll
            for (int s = 0; s < S; s++)
                acc = fmaf(wv[s], usr_feat[((unsigned)ni[s] << 6) | (unsigned)lane], acc);
            agg_iu = acc * inv;
        }

        // KG attention: merge 8 dot-products so lane holds total for s=lane&7
        float agg_ii = 0.f;
        {
            const int4 r0 = ((const int4*)(neigh_ir + v8))[0];
            const int4 r1 = ((const int4*)(neigh_ir + v8))[1];
            const int nr[S] = {r0.x, r0.y, r0.z, r0.w, r1.x, r1.y, r1.z, r1.w};
            float p[S];
            #pragma unroll
            for (int s = 0; s < S; s++) p[s] = u_d * rel_feat[((unsigned)nr[s] << 6) | (unsigned)lane];

            float m1[4];
            #pragma unroll
            for (int i = 0; i < 4; i++) {
                float lo = (lane & 1) ? p[2 * i + 1] : p[2 * i];
                float hi = (lane & 1) ? p[2 * i]     : p[2 * i + 1];
                m1[i] = lo + dppx<XOR1>(hi);
            }
            float m2[2];
            #pragma unroll
            for (int i = 0; i < 2; i++) {
                float lo = (lane & 2) ? m1[2 * i + 1] : m1[2 * i];
                float hi = (lane & 2) ? m1[2 * i]     : m1[2 * i + 1];
                m2[i] = lo + dppx<XOR2>(hi);
            }
            float lo = (lane & 4) ? m2[1] : m2[0];
            float hi = (lane & 4) ? m2[0] : m2[1];
            float att = lo + __shfl_xor(hi, 4);
            att += __shfl_xor(att, 8);
            att += __shfl_xor(att, 16);
            att += __shfl_xor(att, 32);

            float inv;
            const float e = octet_e(att, &inv);
            __threadfence_block();
            if (lane < 8) ew[lane] = e;
            __threadfence_block();
            const float4 eA = ewQ[0], eB = ewQ[1];
            const int4 i0 = ((const int4*)(neigh_ii + v8))[0];
            const int4 i1 = ((const int4*)(neigh_ii + v8))[1];
            const int ni[S] = {i0.x, i0.y, i0.z, i0.w, i1.x, i1.y, i1.z, i1.w};
            const float wv[S] = {eA.x, eA.y, eA.z, eA.w, eB.x, eB.y, eB.z, eB.w};
            float acc = 0.f;
            #pragma unroll
            for (int s = 0; s < S; s++)
                acc = fmaf(wv[s], item_feat[((unsigned)ni[s] << 6) | (unsigned)lane], acc);
            agg_ii = acc * inv;
        }

        // item_h = relu(x @ Wv + bv)
        float hv;
        {
            const float xf = v_d + agg_iu + agg_ii;
            const float xn = dppx<XOR1>(xf);
            __threadfence_block();
            if (!(lane & 1)) xh[lane >> 1] = pk_f16(xf, xn);
            __threadfence_block();
            float a0 = 0.f, a1 = 0.f, a2 = 0.f, a3 = 0.f;
            #pragma unroll
            for (int k = 0; k < 8; k++) {
                const uint4 wq = wvQ[k];
                const uint4 xq = xhQ[k];
                a0 = fdot2(wq.x, xq.x, a0);
                a1 = fdot2(wq.y, xq.y, a1);
                a2 = fdot2(wq.z, xq.z, a2);
                a3 = fdot2(wq.w, xq.w, a3);
            }
            hv = fmaxf((a0 + a1) + (a2 + a3) + bv_l, 0.f);
        }

        // score = sigmoid(dot(user_h, item_h)) * 5
        float p = hu * hv;
        p += dppx<XOR1>(p);
        p += dppx<XOR2>(p);
        p += __shfl_xor(p, 4);
        p += __shfl_xor(p, 8);
        p += __shfl_xor(p, 16);
        p += __shfl_xor(p, 32);
        if (lane == 0) out[b] = 5.0f / (1.0f + __expf(-p));

        b = b2;
        u = u_nxt;
        v = v_nxt;
    }
}

extern "C" void kernel_launch(void* const* d_in, const int* in_sizes, int n_in,
                              void* d_out, int out_size, void* d_ws, size_t ws_size,
                              hipStream_t stream) {
    const int*   u_idx        = (const int*)  d_in[0];
    const int*   v_idx        = (const int*)  d_in[1];
    const float* usr_feat     = (const float*)d_in[2];
    const float* item_feat    = (const float*)d_in[3];
    const float* rel_feat     = (const float*)d_in[4];
    const int*   neigh_uu     = (const int*)  d_in[5];
    const float* neigh_uu_st  = (const float*)d_in[6];
    const int*   neigh_ui     = (const int*)  d_in[7];
    const float* neigh_ui_rat = (const float*)d_in[8];
    const float* neigh_ui_vot = (const float*)d_in[9];
    const float* neigh_ui_tim = (const float*)d_in[10];
    const int*   neigh_iu     = (const int*)  d_in[11];
    const float* neigh_iu_rat = (const float*)d_in[12];
    const float* neigh_iu_vot = (const float*)d_in[13];
    const float* neigh_iu_tim = (const float*)d_in[14];
    const int*   neigh_ii     = (const int*)  d_in[15];
    const int*   neigh_ir     = (const int*)  d_in[16];
    const float* Wu           = (const float*)d_in[17];
    const float* bu           = (const float*)d_in[18];
    const float* Wv           = (const float*)d_in[19];
    const float* bv           = (const float*)d_in[20];
    float*       out          = (float*)d_out;

    const int n = in_sizes[0];
    int blocks = (n + WPB - 1) / WPB;
    if (blocks > GRID) blocks = GRID;
    sestkgcn_kernel<<<blocks, BLOCK, 0, stream>>>(
        u_idx, v_idx, usr_feat, item_feat, rel_feat,
        neigh_uu, neigh_uu_st, neigh_ui, neigh_ui_rat, neigh_ui_vot, neigh_ui_tim,
        neigh_iu, neigh_iu_rat, neigh_iu_vot, neigh_iu_tim, neigh_ii, neigh_ir,
        Wu, bu, Wv, bv, out, n);
}